// Round 3
// baseline (32122.821 us; speedup 1.0000x reference)
//
#include <hip/hip_runtime.h>
#include <math.h>

#define B_    128
#define T_    256
#define DIM_  512
#define HID_  1024
#define OUT_  512
#define TAG_  64
#define K3_   3072
#define NWG_  96

typedef float f32x4 __attribute__((ext_vector_type(4)));
typedef short bf16x8 __attribute__((ext_vector_type(8)));

#define MFMA(a,b,c) __builtin_amdgcn_mfma_f32_16x16x32_bf16(a,b,c,0,0,0)

__device__ __forceinline__ unsigned short f2b(float f){
    unsigned int u = __float_as_uint(f);
    u = (u + 0x7fffu + ((u >> 16) & 1u)) >> 16;   // RNE
    return (unsigned short)u;
}
__device__ __forceinline__ float hardsig(float x){
    return fminf(fmaxf(0.2f*x + 0.5f, 0.f), 1.f);
}
__device__ __forceinline__ bf16x8 ld8(const unsigned short* p){
    return *(const bf16x8*)p;
}
__device__ __forceinline__ bf16x8 ld8f(const float* p){
    float4 a = *(const float4*)p;
    float4 b = *(const float4*)(p + 4);
    bf16x8 r;
    r[0]=(short)f2b(a.x); r[1]=(short)f2b(a.y); r[2]=(short)f2b(a.z); r[3]=(short)f2b(a.w);
    r[4]=(short)f2b(b.x); r[5]=(short)f2b(b.y); r[6]=(short)f2b(b.z); r[7]=(short)f2b(b.w);
    return r;
}

// ---------- grid barrier: monotonic counter, agent scope ----------
__device__ __forceinline__ void gsync(unsigned* cnt, unsigned target){
    __syncthreads();
    if (threadIdx.x == 0){
        __hip_atomic_fetch_add(cnt, 1u, __ATOMIC_RELEASE, __HIP_MEMORY_SCOPE_AGENT);
        while (__hip_atomic_load(cnt, __ATOMIC_ACQUIRE, __HIP_MEMORY_SCOPE_AGENT) < target)
            __builtin_amdgcn_s_sleep(2);
    }
    __syncthreads();
}

// ---------- prep: transpose+convert weights fp32 [K][N-slice] -> bf16 [N][K] ----------
__global__ __launch_bounds__(256) void k_tr(
    unsigned short* __restrict__ dst, const float* __restrict__ src,
    int K, int ld, int col_off)
{
    __shared__ float tile[32][33];
    const int kb = blockIdx.x * 32, nb = blockIdx.y * 32;
    const int tx = threadIdx.x & 31, ty = threadIdx.x >> 5;
    #pragma unroll
    for (int i = 0; i < 4; ++i){
        int kl = ty + i*8;
        tile[kl][tx] = src[(size_t)(kb + kl)*ld + col_off + nb + tx];
    }
    __syncthreads();
    #pragma unroll
    for (int i = 0; i < 4; ++i){
        int nl = ty + i*8;
        dst[(size_t)(nb + nl)*K + kb + tx] = f2b(tile[tx][nl]);
    }
}

__global__ __launch_bounds__(256) void k_cvtx(
    const float4* __restrict__ src, ushort4* __restrict__ dst, int n4)
{
    int i = blockIdx.x * 256 + threadIdx.x;
    if (i < n4){
        float4 v = src[i];
        ushort4 o;
        o.x = f2b(v.x); o.y = f2b(v.y); o.z = f2b(v.z); o.w = f2b(v.w);
        dst[i] = o;
    }
}

__global__ __launch_bounds__(256) void k_init(
    const float* __restrict__ x0, const float* __restrict__ s0,
    unsigned short* __restrict__ xbuf_b, float* __restrict__ sb0,
    unsigned short* __restrict__ s_b)
{
    int i = blockIdx.x * 256 + threadIdx.x;
    if (i < B_*OUT_) xbuf_b[i] = f2b(x0[i]);
    if (i < B_*HID_){ sb0[i] = s0[i]; s_b[i] = f2b(s0[i]); }
}

// ================= persistent cooperative kernel: whole T loop =================
__global__ __launch_bounds__(512, 1) void k_persist(
    const unsigned short* __restrict__ xb16, const float* __restrict__ xf, int use_xb,
    const unsigned short* __restrict__ Wt,  const unsigned short* __restrict__ Vrt,
    const unsigned short* __restrict__ Vzt, const unsigned short* __restrict__ Vst,
    const unsigned short* __restrict__ Urzt,const unsigned short* __restrict__ Ust,
    const unsigned short* __restrict__ Wxt,
    const float* __restrict__ bias, const float* __restrict__ bx,
    const float* __restrict__ Wy,   const float* __restrict__ by,
    unsigned short* __restrict__ xbuf_b, unsigned short* __restrict__ s_b,
    unsigned short* __restrict__ rs_b,
    float* __restrict__ sb0, float* __restrict__ sb1,
    float* __restrict__ pre, float* __restrict__ logits,
    float* __restrict__ out, unsigned* __restrict__ cnt)
{
    const int wg   = blockIdx.x;      // 0..95
    const int tid  = threadIdx.x;     // 0..511
    const int lane = tid & 63;
    const int wv   = tid >> 6;        // wave 0..7 (= m-tile)
    const int l15  = lane & 15;
    const int kch  = lane >> 4;
    unsigned target = 0;

    __shared__ float sm_xs[512];
    __shared__ float sm_red[512];

    for (int t = 0; t < T_; ++t){
        const float* sp = (t & 1) ? sb1 : sb0;
        float*       sn = (t & 1) ? sb0 : sb1;

        // ---------------- phase A: pre / rs ----------------
        {
            const int n0   = wg * 32;
            const int nseg = n0 >> 10;          // 0=r 1=z 2=xs
            const int arow = wv*16 + l15;
            f32x4 acc0 = {0.f,0.f,0.f,0.f};
            f32x4 acc1 = {0.f,0.f,0.f,0.f};
            // seg0: x_tm1 @ W  (K=512)
            {
                const unsigned short* ab = xbuf_b + arow*OUT_ + kch*8;
                const unsigned short* b0 = Wt + (size_t)(n0 + l15)*OUT_ + kch*8;
                const unsigned short* b1 = b0 + 16*OUT_;
                #pragma unroll 4
                for (int kb = 0; kb < OUT_; kb += 32){
                    bf16x8 a = ld8(ab + kb);
                    acc0 = MFMA(a, ld8(b0 + kb), acc0);
                    acc1 = MFMA(a, ld8(b1 + kb), acc1);
                }
            }
            // seg1: inp_t @ V  (K=512)
            {
                const unsigned short* Vt = (nseg==0) ? Vrt : ((nseg==1) ? Vzt : Vst);
                const int nl = n0 - (nseg << 10);
                const unsigned short* b0 = Vt + (size_t)(nl + l15)*DIM_ + kch*8;
                const unsigned short* b1 = b0 + 16*DIM_;
                if (use_xb){
                    const unsigned short* ab = xb16 + ((size_t)arow*T_ + t)*DIM_ + kch*8;
                    #pragma unroll 4
                    for (int kb = 0; kb < DIM_; kb += 32){
                        bf16x8 a = ld8(ab + kb);
                        acc0 = MFMA(a, ld8(b0 + kb), acc0);
                        acc1 = MFMA(a, ld8(b1 + kb), acc1);
                    }
                } else {
                    const float* af = xf + ((size_t)arow*T_ + t)*DIM_ + kch*8;
                    #pragma unroll 2
                    for (int kb = 0; kb < DIM_; kb += 32){
                        bf16x8 a = ld8f(af + kb);
                        acc0 = MFMA(a, ld8(b0 + kb), acc0);
                        acc1 = MFMA(a, ld8(b1 + kb), acc1);
                    }
                }
            }
            // seg2: s_tm1 @ U_rz  (K=1024, r/z only)
            if (nseg < 2){
                const unsigned short* ab = s_b + arow*HID_ + kch*8;
                const unsigned short* b0 = Urzt + (size_t)(n0 + l15)*HID_ + kch*8;
                const unsigned short* b1 = b0 + 16*HID_;
                #pragma unroll 4
                for (int kb = 0; kb < HID_; kb += 32){
                    bf16x8 a = ld8(ab + kb);
                    acc0 = MFMA(a, ld8(b0 + kb), acc0);
                    acc1 = MFMA(a, ld8(b1 + kb), acc1);
                }
            }
            const int rbase = wv*16 + kch*4;
            #pragma unroll
            for (int half = 0; half < 2; ++half){
                f32x4 acc = half ? acc1 : acc0;
                const int col = n0 + half*16 + l15;
                const float bv = bias[col];
                #pragma unroll
                for (int q = 0; q < 4; ++q){
                    const int r = rbase + q;
                    const float v = acc[q] + bv;
                    if (nseg == 0){
                        float rs = hardsig(v) * sp[r*HID_ + col];
                        rs_b[r*HID_ + col] = f2b(rs);
                    } else {
                        pre[(size_t)r*K3_ + col] = v;
                    }
                }
            }
        }
        target += NWG_; gsync(cnt, target);

        // ---------------- phase B: s update ----------------
        if (wg < 32){
            const int n0 = wg * 32;
            const int arow = wv*16 + l15;
            f32x4 acc0 = {0.f,0.f,0.f,0.f};
            f32x4 acc1 = {0.f,0.f,0.f,0.f};
            const unsigned short* ab = rs_b + arow*HID_ + kch*8;
            const unsigned short* b0 = Ust + (size_t)(n0 + l15)*HID_ + kch*8;
            const unsigned short* b1 = b0 + 16*HID_;
            #pragma unroll 4
            for (int kb = 0; kb < HID_; kb += 32){
                bf16x8 a = ld8(ab + kb);
                acc0 = MFMA(a, ld8(b0 + kb), acc0);
                acc1 = MFMA(a, ld8(b1 + kb), acc1);
            }
            const int rbase = wv*16 + kch*4;
            #pragma unroll
            for (int half = 0; half < 2; ++half){
                f32x4 acc = half ? acc1 : acc0;
                const int col = n0 + half*16 + l15;
                #pragma unroll
                for (int q = 0; q < 4; ++q){
                    const int r = rbase + q;
                    float z  = hardsig(pre[(size_t)r*K3_ + HID_ + col]);
                    float xs = pre[(size_t)r*K3_ + 2*HID_ + col];
                    float so = sp[r*HID_ + col];
                    float s1 = tanhf(xs + acc[q]);
                    float snv = (1.f - z)*so + z*s1;
                    sn[r*HID_ + col] = snv;
                    s_b[r*HID_ + col] = f2b(snv);
                }
            }
        }
        target += NWG_; gsync(cnt, target);

        // ---------------- phase C: logits ----------------
        if (wg < 16){
            const int n0 = wg * 32;
            const int arow = wv*16 + l15;
            f32x4 acc0 = {0.f,0.f,0.f,0.f};
            f32x4 acc1 = {0.f,0.f,0.f,0.f};
            const unsigned short* ab = s_b + arow*HID_ + kch*8;
            const unsigned short* b0 = Wxt + (size_t)(n0 + l15)*HID_ + kch*8;
            const unsigned short* b1 = b0 + 16*HID_;
            #pragma unroll 4
            for (int kb = 0; kb < HID_; kb += 32){
                bf16x8 a = ld8(ab + kb);
                acc0 = MFMA(a, ld8(b0 + kb), acc0);
                acc1 = MFMA(a, ld8(b1 + kb), acc1);
            }
            const int rbase = wv*16 + kch*4;
            #pragma unroll
            for (int half = 0; half < 2; ++half){
                f32x4 acc = half ? acc1 : acc0;
                const int col = n0 + half*16 + l15;
                #pragma unroll
                for (int q = 0; q < 4; ++q){
                    logits[(rbase + q)*OUT_ + col] = acc[q] + bx[col];
                }
            }
        }
        target += NWG_; gsync(cnt, target);

        // ---------------- phase D: softmax -> x_t ; x_t@Wy -> softmax -> out ----------------
        for (int r = wg; r < B_; r += NWG_){
            float v = logits[r*OUT_ + tid];
            // row max
            float m = v;
            #pragma unroll
            for (int off = 32; off > 0; off >>= 1) m = fmaxf(m, __shfl_xor(m, off));
            if (lane == 0) sm_red[wv] = m;
            __syncthreads();
            float mx = sm_red[0];
            #pragma unroll
            for (int q = 1; q < 8; ++q) mx = fmaxf(mx, sm_red[q]);
            float e = expf(v - mx);
            float ssum = e;
            #pragma unroll
            for (int off = 32; off > 0; off >>= 1) ssum += __shfl_xor(ssum, off);
            __syncthreads();
            if (lane == 0) sm_red[wv] = ssum;
            __syncthreads();
            float tot = 0.f;
            #pragma unroll
            for (int q = 0; q < 8; ++q) tot += sm_red[q];
            float xv = e / tot;
            sm_xs[tid] = xv;
            xbuf_b[r*OUT_ + tid] = f2b(xv);
            __syncthreads();
            // x_t @ Wy : tag = tid&63, 8 K-parts of 64
            const int tag = tid & 63, part = tid >> 6;
            float p = 0.f;
            const int k0 = part * 64;
            #pragma unroll 4
            for (int k = k0; k < k0 + 64; ++k) p += sm_xs[k] * Wy[k*TAG_ + tag];
            sm_red[tid] = p;
            __syncthreads();
            if (tid < 64){
                float tl = by[tid];
                #pragma unroll
                for (int q = 0; q < 8; ++q) tl += sm_red[q*64 + tid];
                float wm = tl;
                #pragma unroll
                for (int off = 32; off > 0; off >>= 1) wm = fmaxf(wm, __shfl_xor(wm, off));
                float ex = expf(tl - wm);
                float sm = ex;
                #pragma unroll
                for (int off = 32; off > 0; off >>= 1) sm += __shfl_xor(sm, off);
                out[((long)r*T_ + t)*TAG_ + tid] = ex / sm;
            }
            __syncthreads();
        }
        target += NWG_; gsync(cnt, target);
    }
}

// ---------------- fallback kernels (round-2 path) ----------------
__global__ __launch_bounds__(256) void k_gemmA(
    const unsigned short* __restrict__ xbuf_b, const unsigned short* __restrict__ xb16,
    const float* __restrict__ xf, const unsigned short* __restrict__ s_b,
    const float* __restrict__ sp, const unsigned short* __restrict__ Wt,
    const unsigned short* __restrict__ Vrt, const unsigned short* __restrict__ Vzt,
    const unsigned short* __restrict__ Vst, const unsigned short* __restrict__ Urzt,
    const float* __restrict__ bias, float* __restrict__ pre,
    unsigned short* __restrict__ rs_b, int t, int use_xb)
{
    const int wid  = (blockIdx.x * 256 + threadIdx.x) >> 6;
    const int lane = threadIdx.x & 63;
    const int mt = wid & 7, nt = wid >> 3;
    const int n0 = nt * 32, nseg = n0 >> 10;
    const int l15 = lane & 15, kch = lane >> 4;
    const int arow = mt*16 + l15;
    f32x4 acc0 = {0.f,0.f,0.f,0.f}, acc1 = {0.f,0.f,0.f,0.f};
    {
        const unsigned short* ab = xbuf_b + arow*OUT_ + kch*8;
        const unsigned short* b0 = Wt + (size_t)(n0 + l15)*OUT_ + kch*8;
        const unsigned short* b1 = b0 + 16*OUT_;
        #pragma unroll 4
        for (int kb = 0; kb < OUT_; kb += 32){
            bf16x8 a = ld8(ab + kb);
            acc0 = MFMA(a, ld8(b0 + kb), acc0);
            acc1 = MFMA(a, ld8(b1 + kb), acc1);
        }
    }
    {
        const unsigned short* Vt = (nseg==0) ? Vrt : ((nseg==1) ? Vzt : Vst);
        const int nl = n0 - (nseg << 10);
        const unsigned short* b0 = Vt + (size_t)(nl + l15)*DIM_ + kch*8;
        const unsigned short* b1 = b0 + 16*DIM_;
        if (use_xb){
            const unsigned short* ab = xb16 + ((size_t)arow*T_ + t)*DIM_ + kch*8;
            #pragma unroll 4
            for (int kb = 0; kb < DIM_; kb += 32){
                bf16x8 a = ld8(ab + kb);
                acc0 = MFMA(a, ld8(b0 + kb), acc0);
                acc1 = MFMA(a, ld8(b1 + kb), acc1);
            }
        } else {
            const float* af = xf + ((size_t)arow*T_ + t)*DIM_ + kch*8;
            #pragma unroll 2
            for (int kb = 0; kb < DIM_; kb += 32){
                bf16x8 a = ld8f(af + kb);
                acc0 = MFMA(a, ld8(b0 + kb), acc0);
                acc1 = MFMA(a, ld8(b1 + kb), acc1);
            }
        }
    }
    if (nseg < 2){
        const unsigned short* ab = s_b + arow*HID_ + kch*8;
        const unsigned short* b0 = Urzt + (size_t)(n0 + l15)*HID_ + kch*8;
        const unsigned short* b1 = b0 + 16*HID_;
        #pragma unroll 4
        for (int kb = 0; kb < HID_; kb += 32){
            bf16x8 a = ld8(ab + kb);
            acc0 = MFMA(a, ld8(b0 + kb), acc0);
            acc1 = MFMA(a, ld8(b1 + kb), acc1);
        }
    }
    const int rbase = mt*16 + kch*4;
    #pragma unroll
    for (int half = 0; half < 2; ++half){
        f32x4 acc = half ? acc1 : acc0;
        const int col = n0 + half*16 + l15;
        const float bv = bias[col];
        #pragma unroll
        for (int q = 0; q < 4; ++q){
            const int r = rbase + q;
            const float v = acc[q] + bv;
            if (nseg == 0){
                float rs = hardsig(v) * sp[r*HID_ + col];
                rs_b[r*HID_ + col] = f2b(rs);
            } else {
                pre[(size_t)r*K3_ + col] = v;
            }
        }
    }
}

__global__ __launch_bounds__(256) void k_gemmB(
    const unsigned short* __restrict__ rs_b, const unsigned short* __restrict__ Ust,
    const float* __restrict__ pre, const float* __restrict__ sp,
    float* __restrict__ snf, unsigned short* __restrict__ s_b)
{
    const int wid  = (blockIdx.x * 256 + threadIdx.x) >> 6;
    const int lane = threadIdx.x & 63;
    const int mt = wid & 7, nt = wid >> 3;
    const int n0 = nt * 32;
    const int l15 = lane & 15, kch = lane >> 4;
    const int arow = mt*16 + l15;
    f32x4 acc0 = {0.f,0.f,0.f,0.f}, acc1 = {0.f,0.f,0.f,0.f};
    const unsigned short* ab = rs_b + arow*HID_ + kch*8;
    const unsigned short* b0 = Ust + (size_t)(n0 + l15)*HID_ + kch*8;
    const unsigned short* b1 = b0 + 16*HID_;
    #pragma unroll 4
    for (int kb = 0; kb < HID_; kb += 32){
        bf16x8 a = ld8(ab + kb);
        acc0 = MFMA(a, ld8(b0 + kb), acc0);
        acc1 = MFMA(a, ld8(b1 + kb), acc1);
    }
    const int rbase = mt*16 + kch*4;
    #pragma unroll
    for (int half = 0; half < 2; ++half){
        f32x4 acc = half ? acc1 : acc0;
        const int col = n0 + half*16 + l15;
        #pragma unroll
        for (int q = 0; q < 4; ++q){
            const int r = rbase + q;
            float z  = hardsig(pre[(size_t)r*K3_ + HID_ + col]);
            float xs = pre[(size_t)r*K3_ + 2*HID_ + col];
            float so = sp[r*HID_ + col];
            float s1 = tanhf(xs + acc[q]);
            float snv = (1.f - z)*so + z*s1;
            snf[r*HID_ + col] = snv;
            s_b[r*HID_ + col] = f2b(snv);
        }
    }
}

__global__ __launch_bounds__(256) void k_gemmC(
    const unsigned short* __restrict__ s_b, const unsigned short* __restrict__ Wxt,
    const float* __restrict__ bx, float* __restrict__ logits)
{
    const int wid  = (blockIdx.x * 256 + threadIdx.x) >> 6;
    const int lane = threadIdx.x & 63;
    const int mt = wid & 7, nt = wid >> 3;
    const int n0 = nt * 32;
    const int l15 = lane & 15, kch = lane >> 4;
    const int arow = mt*16 + l15;
    f32x4 acc0 = {0.f,0.f,0.f,0.f}, acc1 = {0.f,0.f,0.f,0.f};
    const unsigned short* ab = s_b + arow*HID_ + kch*8;
    const unsigned short* b0 = Wxt + (size_t)(n0 + l15)*HID_ + kch*8;
    const unsigned short* b1 = b0 + 16*HID_;
    #pragma unroll 4
    for (int kb = 0; kb < HID_; kb += 32){
        bf16x8 a = ld8(ab + kb);
        acc0 = MFMA(a, ld8(b0 + kb), acc0);
        acc1 = MFMA(a, ld8(b1 + kb), acc1);
    }
    const int rbase = mt*16 + kch*4;
    #pragma unroll
    for (int half = 0; half < 2; ++half){
        f32x4 acc = half ? acc1 : acc0;
        const int col = n0 + half*16 + l15;
        #pragma unroll
        for (int q = 0; q < 4; ++q){
            logits[(rbase + q)*OUT_ + col] = acc[q] + bx[col];
        }
    }
}

__global__ __launch_bounds__(256) void k_soft(
    const float* __restrict__ logits, const float* __restrict__ Wy,
    const float* __restrict__ by, unsigned short* __restrict__ xbuf_b,
    float* __restrict__ out, int t)
{
    __shared__ float xs[512];
    __shared__ float red[256];
    const int r = blockIdx.x, tid = threadIdx.x;
    float v0 = logits[r*OUT_ + tid];
    float v1 = logits[r*OUT_ + 256 + tid];
    red[tid] = fmaxf(v0, v1);
    __syncthreads();
    for (int s = 128; s > 0; s >>= 1){
        if (tid < s) red[tid] = fmaxf(red[tid], red[tid+s]);
        __syncthreads();
    }
    float mx = red[0];
    __syncthreads();
    float e0 = expf(v0 - mx), e1 = expf(v1 - mx);
    red[tid] = e0 + e1;
    __syncthreads();
    for (int s = 128; s > 0; s >>= 1){
        if (tid < s) red[tid] += red[tid+s];
        __syncthreads();
    }
    float inv = 1.f / red[0];
    __syncthreads();
    float x0v = e0*inv, x1v = e1*inv;
    xs[tid] = x0v; xs[tid + 256] = x1v;
    xbuf_b[r*OUT_ + tid] = f2b(x0v);
    xbuf_b[r*OUT_ + 256 + tid] = f2b(x1v);
    __syncthreads();
    const int j = tid & 63, part = tid >> 6;
    float p = 0.f;
    const int k0 = part * 128;
    #pragma unroll 4
    for (int k = k0; k < k0 + 128; ++k) p += xs[k] * Wy[k*TAG_ + j];
    red[tid] = p;
    __syncthreads();
    if (tid < 64){
        float tl = red[tid] + red[tid+64] + red[tid+128] + red[tid+192] + by[tid];
        float wm = tl;
        #pragma unroll
        for (int off = 32; off > 0; off >>= 1) wm = fmaxf(wm, __shfl_xor(wm, off));
        float ex = expf(tl - wm);
        float sm = ex;
        #pragma unroll
        for (int off = 32; off > 0; off >>= 1) sm += __shfl_xor(sm, off);
        out[((long)r*T_ + t)*TAG_ + tid] = ex / sm;
    }
}

extern "C" void kernel_launch(void* const* d_in, const int* in_sizes, int n_in,
                              void* d_out, int out_size, void* d_ws, size_t ws_size,
                              hipStream_t stream){
    const float* x   = (const float*)d_in[0];
    const float* x0  = (const float*)d_in[1];
    const float* s0  = (const float*)d_in[2];
    const float* W   = (const float*)d_in[3];
    const float* U   = (const float*)d_in[4];
    const float* b   = (const float*)d_in[5];
    const float* Wx  = (const float*)d_in[6];
    const float* bx  = (const float*)d_in[7];
    const float* Vr  = (const float*)d_in[8];
    const float* Vz  = (const float*)d_in[9];
    const float* Vs  = (const float*)d_in[10];
    const float* Wy  = (const float*)d_in[11];
    const float* by  = (const float*)d_in[12];
    float* out = (float*)d_out;

    char* ws = (char*)d_ws;
    size_t off = 0;
    auto alloc = [&](size_t bytes) -> size_t {
        size_t o = off; off = (off + bytes + 255) & ~(size_t)255; return o;
    };
    unsigned* scnt        = (unsigned*)(ws + alloc(256));
    unsigned short* Wt    = (unsigned short*)(ws + alloc((size_t)K3_*OUT_*2));
    unsigned short* Urzt  = (unsigned short*)(ws + alloc((size_t)2048*HID_*2));
    unsigned short* Ust   = (unsigned short*)(ws + alloc((size_t)HID_*HID_*2));
    unsigned short* Vrt   = (unsigned short*)(ws + alloc((size_t)HID_*DIM_*2));
    unsigned short* Vzt   = (unsigned short*)(ws + alloc((size_t)HID_*DIM_*2));
    unsigned short* Vst   = (unsigned short*)(ws + alloc((size_t)HID_*DIM_*2));
    unsigned short* Wxt   = (unsigned short*)(ws + alloc((size_t)OUT_*HID_*2));
    unsigned short* xbuf_b= (unsigned short*)(ws + alloc((size_t)B_*OUT_*2));
    unsigned short* s_b   = (unsigned short*)(ws + alloc((size_t)B_*HID_*2));
    unsigned short* rs_b  = (unsigned short*)(ws + alloc((size_t)B_*HID_*2));
    float* sb0    = (float*)(ws + alloc((size_t)B_*HID_*4));
    float* sb1    = (float*)(ws + alloc((size_t)B_*HID_*4));
    float* pre    = (float*)(ws + alloc((size_t)B_*K3_*4));
    float* logits = (float*)(ws + alloc((size_t)B_*OUT_*4));
    unsigned short* xb16 = (unsigned short*)(ws + alloc((size_t)B_*T_*DIM_*2));
    int use_xb = (off <= ws_size) ? 1 : 0;

    hipMemsetAsync(scnt, 0, 256, stream);
    k_tr<<<dim3(OUT_/32, K3_/32),  256, 0, stream>>>(Wt,   W,  OUT_, K3_, 0);
    k_tr<<<dim3(HID_/32, 2048/32), 256, 0, stream>>>(Urzt, U,  HID_, K3_, 0);
    k_tr<<<dim3(HID_/32, HID_/32), 256, 0, stream>>>(Ust,  U,  HID_, K3_, 2048);
    k_tr<<<dim3(DIM_/32, HID_/32), 256, 0, stream>>>(Vrt,  Vr, DIM_, HID_, 0);
    k_tr<<<dim3(DIM_/32, HID_/32), 256, 0, stream>>>(Vzt,  Vz, DIM_, HID_, 0);
    k_tr<<<dim3(DIM_/32, HID_/32), 256, 0, stream>>>(Vst,  Vs, DIM_, HID_, 0);
    k_tr<<<dim3(HID_/32, OUT_/32), 256, 0, stream>>>(Wxt,  Wx, HID_, OUT_, 0);
    if (use_xb){
        int n4 = B_*T_*DIM_/4;
        k_cvtx<<<(n4 + 255)/256, 256, 0, stream>>>((const float4*)x, (ushort4*)xb16, n4);
    }
    k_init<<<(B_*HID_ + 255)/256, 256, 0, stream>>>(x0, s0, xbuf_b, sb0, s_b);

    // ---- persistent cooperative kernel ----
    const unsigned short* xb16c = xb16;
    void* kargs[] = {
        (void*)&xb16c, (void*)&x, (void*)&use_xb,
        (void*)&Wt, (void*)&Vrt, (void*)&Vzt, (void*)&Vst, (void*)&Urzt, (void*)&Ust,
        (void*)&Wxt, (void*)&b, (void*)&bx, (void*)&Wy, (void*)&by,
        (void*)&xbuf_b, (void*)&s_b, (void*)&rs_b,
        (void*)&sb0, (void*)&sb1, (void*)&pre, (void*)&logits,
        (void*)&out, (void*)&scnt
    };
    hipError_t err = hipLaunchCooperativeKernel((const void*)k_persist,
                                                dim3(NWG_), dim3(512),
                                                kargs, 0, stream);
    if (err != hipSuccess){
        // fallback: per-step kernel loop (round-2 path)
        for (int t = 0; t < T_; ++t){
            float* sp = (t & 1) ? sb1 : sb0;
            float* sn = (t & 1) ? sb0 : sb1;
            k_gemmA<<<192, 256, 0, stream>>>(xbuf_b, xb16, x, s_b, sp,
                                             Wt, Vrt, Vzt, Vst, Urzt, b,
                                             pre, rs_b, t, use_xb);
            k_gemmB<<<64, 256, 0, stream>>>(rs_b, Ust, pre, sp, sn, s_b);
            k_gemmC<<<32, 256, 0, stream>>>(s_b, Wxt, bx, logits);
            k_soft <<<128, 256, 0, stream>>>(logits, Wy, by, xbuf_b, out, t);
        }
    }
}